// Round 2
// baseline (3253.249 us; speedup 1.0000x reference)
//
#include <hip/hip_runtime.h>
#include <math.h>

#define HDIM   7168
#define NEXP   256
#define NTOK   16384
#define TM     64
#define TK     32
#define KTILES (HDIM / TK)   // 224

// ---------------------------------------------------------------------------
// Phase 1: scores_for_choice[t][e] = sigmoid( X[t,:] . W[:,e] ) + bias[e]
// fp32 vector-ALU GEMM (no fp32 MFMA on CDNA4).
// 512 threads = 8 waves/block; each wave owns 8 wave-uniform rows of A
// (scalar s_load broadcast -> SGPR operand in v_fmac) and all 256 cols
// (4 cols/lane). B staged in LDS; fragment read is one conflict-free
// ds_read_b128 per k-step (16B lane stride covers all 32 banks).
// 2-level accumulation keeps logit error ~1e-6 (top-k decisions stable).
// ---------------------------------------------------------------------------
__global__ __launch_bounds__(512, 2) void gemm_scores(
    const float* __restrict__ A,      // [NTOK][HDIM]
    const float* __restrict__ W,      // [HDIM][NEXP]
    const float* __restrict__ bias,   // [NEXP]
    float* __restrict__ scores)       // [NTOK][NEXP]
{
  __shared__ float b_s[TK][NEXP];     // 32 KiB

  const int tid  = threadIdx.x;
  const int m0   = blockIdx.x * TM;
  const int wv   = __builtin_amdgcn_readfirstlane(tid >> 6);  // wave id 0..7 (uniform)
  const int colg = tid & 63;                                  // cols 4*colg..+3

  // B staging coords: thread loads rows {bk, bk+8, bk+16, bk+24}, 16B at col bn
  const int bk = tid >> 6;
  const int bn = (tid & 63) << 2;

  // wave-uniform A row base: rows m0 + 8*wv .. +7
  const float* Arow = A + (size_t)(m0 + (wv << 3)) * HDIM;

  float4 pb[4];
#pragma unroll
  for (int i = 0; i < 4; ++i)
    pb[i] = *(const float4*)(W + (size_t)(bk + 8 * i) * NEXP + bn);

  float accm[8][4];
#pragma unroll
  for (int r = 0; r < 8; ++r)
#pragma unroll
    for (int c = 0; c < 4; ++c) accm[r][c] = 0.f;

  for (int kt = 0; kt < KTILES; ++kt) {
    __syncthreads();
#pragma unroll
    for (int i = 0; i < 4; ++i)
      *(float4*)(&b_s[bk + 8 * i][bn]) = pb[i];
    __syncthreads();

    // prefetch next B k-tile into registers (in flight during compute)
    if (kt + 1 < KTILES) {
      const float* Wp = W + (size_t)(kt + 1) * TK * NEXP + (size_t)bk * NEXP + bn;
#pragma unroll
      for (int i = 0; i < 4; ++i)
        pb[i] = *(const float4*)(Wp + (size_t)(8 * i) * NEXP);
    }

    float acct[8][4];
#pragma unroll
    for (int r = 0; r < 8; ++r)
#pragma unroll
      for (int c = 0; c < 4; ++c) acct[r][c] = 0.f;

    const float* Ak = Arow + (size_t)kt * TK;
#pragma unroll
    for (int kc = 0; kc < TK; kc += 4) {
      // wave-uniform A chunk: 8 rows x 4 k  (scalar loads -> SGPRs)
      float a[8][4];
#pragma unroll
      for (int r = 0; r < 8; ++r) {
        a[r][0] = Ak[(size_t)r * HDIM + kc + 0];
        a[r][1] = Ak[(size_t)r * HDIM + kc + 1];
        a[r][2] = Ak[(size_t)r * HDIM + kc + 2];
        a[r][3] = Ak[(size_t)r * HDIM + kc + 3];
      }
#pragma unroll
      for (int j = 0; j < 4; ++j) {
        const float4 b = *(const float4*)(&b_s[kc + j][colg << 2]);
#pragma unroll
        for (int r = 0; r < 8; ++r) {
          acct[r][0] = fmaf(a[r][j], b.x, acct[r][0]);
          acct[r][1] = fmaf(a[r][j], b.y, acct[r][1]);
          acct[r][2] = fmaf(a[r][j], b.z, acct[r][2]);
          acct[r][3] = fmaf(a[r][j], b.w, acct[r][3]);
        }
      }
    }
#pragma unroll
    for (int r = 0; r < 8; ++r)
#pragma unroll
      for (int c = 0; c < 4; ++c) accm[r][c] += acct[r][c];
  }

  // epilogue: sigmoid + bias
  const float4 bb = *(const float4*)(bias + (colg << 2));
#pragma unroll
  for (int r = 0; r < 8; ++r) {
    const int row = m0 + (wv << 3) + r;
    float4 o;
    o.x = 1.0f / (1.0f + expf(-accm[r][0])) + bb.x;
    o.y = 1.0f / (1.0f + expf(-accm[r][1])) + bb.y;
    o.z = 1.0f / (1.0f + expf(-accm[r][2])) + bb.z;
    o.w = 1.0f / (1.0f + expf(-accm[r][3])) + bb.w;
    *(float4*)(scores + (size_t)row * NEXP + (colg << 2)) = o;
  }
}

// ---------------------------------------------------------------------------
// Phase 2: wave-per-token routing. One float4 load/lane puts the whole
// 256-score row in wave registers (lane l holds experts 4l..4l+3; group g is
// lanes 8g..8g+7). Group top-2 via shfl_xor merge; masked top-8 via 8
// butterfly max-extractions. Tie-breaking replicates jax.lax.top_k
// (descending value, ascending index on equality).
// ---------------------------------------------------------------------------
__global__ __launch_bounds__(256) void route_kernel(
    const float* __restrict__ scores,   // [NTOK][NEXP]
    float* __restrict__ out_idx,        // [NTOK][8] (indices as float)
    float* __restrict__ out_w)          // [NTOK][8]
{
  const int lane = threadIdx.x & 63;
  const int t    = blockIdx.x * 4 + (threadIdx.x >> 6);

  const float4 v4 = ((const float4*)(scores + (size_t)t * NEXP))[lane];

  // sorted top-2 of this lane's 4 experts
  float m1 = fmaxf(v4.x, v4.y), m2 = fminf(v4.x, v4.y);
  if (v4.z > m1) { m2 = m1; m1 = v4.z; } else m2 = fmaxf(m2, v4.z);
  if (v4.w > m1) { m2 = m1; m1 = v4.w; } else m2 = fmaxf(m2, v4.w);

  // merge across the 8-lane group (xor 1,2,4 stays within the group)
#pragma unroll
  for (int d = 1; d < 8; d <<= 1) {
    const float o1 = __shfl_xor(m1, d);
    const float o2 = __shfl_xor(m2, d);
    if (o1 > m1) { m2 = fmaxf(m1, o2); m1 = o1; } else m2 = fmaxf(m2, o1);
  }
  const float gsc = m1 + m2;   // group score (largest + second)

  // every lane gathers all 8 group scores, picks top-4 groups
  float gv[8];
#pragma unroll
  for (int g = 0; g < 8; ++g) gv[g] = __shfl(gsc, g << 3);
  int selmask = 0;
#pragma unroll
  for (int k = 0; k < 4; ++k) {
    float best = -3.0e38f; int bg = 0;
#pragma unroll
    for (int g = 0; g < 8; ++g)
      if (!((selmask >> g) & 1) && gv[g] > best) { best = gv[g]; bg = g; }
    selmask |= 1 << bg;
  }

  // masked candidates (unselected groups -> exactly 0.0, like the reference)
  const bool sel = (selmask >> (lane >> 3)) & 1;
  float cv0 = sel ? v4.x : 0.0f;
  float cv1 = sel ? v4.y : 0.0f;
  float cv2 = sel ? v4.z : 0.0f;
  float cv3 = sel ? v4.w : 0.0f;

  int ti[8]; float tw[8];
#pragma unroll
  for (int k = 0; k < 8; ++k) {
    // lane-local max (ascending j + strict > => smallest index on ties)
    float bv = cv0; int bj = 0;
    if (cv1 > bv) { bv = cv1; bj = 1; }
    if (cv2 > bv) { bv = cv2; bj = 2; }
    if (cv3 > bv) { bv = cv3; bj = 3; }
    int bi = (lane << 2) + bj;
    // wave butterfly max with (value desc, index asc) ordering
#pragma unroll
    for (int d = 32; d >= 1; d >>= 1) {
      const float ov = __shfl_xor(bv, d);
      const int   oi = __shfl_xor(bi, d);
      if (ov > bv || (ov == bv && oi < bi)) { bv = ov; bi = oi; }
    }
    ti[k] = bi;                       // uniform across wave
    const int owner = bi >> 2, bj2 = bi & 3;
    // weight gathers from the UNMASKED scores
    const float pick = (bj2 == 0) ? v4.x : (bj2 == 1) ? v4.y
                     : (bj2 == 2) ? v4.z : v4.w;
    tw[k] = __shfl(pick, owner);
    if (lane == owner) {              // consume
      if      (bj2 == 0) cv0 = -3.0e38f;
      else if (bj2 == 1) cv1 = -3.0e38f;
      else if (bj2 == 2) cv2 = -3.0e38f;
      else               cv3 = -3.0e38f;
    }
  }

  float denom = 0.f;
#pragma unroll
  for (int k = 0; k < 8; ++k) denom += tw[k];
  denom += 1e-20f;
  const float inv = 2.5f / denom;

  if (lane == 0) {
    float* oi = out_idx + (size_t)t * 8;
    float* ow = out_w   + (size_t)t * 8;
    *(float4*)(oi + 0) = make_float4((float)ti[0], (float)ti[1], (float)ti[2], (float)ti[3]);
    *(float4*)(oi + 4) = make_float4((float)ti[4], (float)ti[5], (float)ti[6], (float)ti[7]);
    *(float4*)(ow + 0) = make_float4(tw[0] * inv, tw[1] * inv, tw[2] * inv, tw[3] * inv);
    *(float4*)(ow + 4) = make_float4(tw[4] * inv, tw[5] * inv, tw[6] * inv, tw[7] * inv);
  }
}

// ---------------------------------------------------------------------------
extern "C" void kernel_launch(void* const* d_in, const int* in_sizes, int n_in,
                              void* d_out, int out_size, void* d_ws, size_t ws_size,
                              hipStream_t stream)
{
  const float* hs   = (const float*)d_in[0];   // [4,4096,7168] fp32
  const float* w    = (const float*)d_in[1];   // [7168,256]    fp32
  const float* bias = (const float*)d_in[2];   // [256]         fp32
  float* out   = (float*)d_out;                // [16384*8 idx][16384*8 w] fp32
  float* score = (float*)d_ws;                 // scratch: 16 MiB

  gemm_scores<<<NTOK / TM, 512, 0, stream>>>(hs, w, bias, score);
  route_kernel<<<NTOK / 4, 256, 0, stream>>>(score, out, out + (size_t)NTOK * 8);
}